// Round 1
// baseline (93.566 us; speedup 1.0000x reference)
//
#include <hip/hip_runtime.h>

#define GRID_N 16384
#define NLAYERS 8
#define NPOS 32
#define BATCH 32
#define MW 4096          // output width
#define TILE 64
#define HALO 16          // 2 * NLAYERS
#define WBUF (TILE + 2 * HALO)  // 96

// Multilinear-lerp ASIC automaton: 8 layers fused in one kernel.
// Each block: 64-column tile (+16 halo/side) x all 32 batches.
// 256 threads = 4 waves; wave ty handles batches ty*8..ty*8+7, lane = column.
__global__ __launch_bounds__(256) void ASIC_44186623541335_kernel(
    const float* __restrict__ x,    // (32, 4096)
    const float* __restrict__ tg,   // (8, 32, 16384) raw logits
    float* __restrict__ out)        // (32, 4096)
{
    __shared__ float st[BATCH][WBUF];

    const int tid = threadIdx.x;
    const int tx  = tid & 63;       // lane / column-in-pass
    const int ty  = tid >> 6;       // 0..3 -> batches ty*8..+7
    const int start = blockIdx.x * TILE;

    // ---- init state: embed x at stride 4, zeros elsewhere ----
    for (int f = tid; f < BATCH * WBUF; f += 256) {
        const int b = f / WBUF;
        const int j = f - b * WBUF;
        const int g = (start - HALO + j) & (GRID_N - 1);
        float v = 0.0f;
        if ((g & 3) == 0) v = x[b * MW + (g >> 2)];
        st[b][j] = v;
    }
    __syncthreads();

    float newv[2][8];   // [pass][batch-in-group], statically indexed

    for (int l = 0; l < NLAYERS; ++l) {
        const int h     = 2 * (NLAYERS - 1 - l);  // halo still needed after this layer
        const int ncols = TILE + 2 * h;           // columns computed this layer
        const int jbase = HALO - h;               // local index of first computed col
        const float* twl = tg + (size_t)l * NPOS * GRID_N;

        #pragma unroll
        for (int p = 0; p < 2; ++p) {
            const int ci = tx + p * 64;
            if (ci < ncols) {
                const int j = jbase + ci;
                const int g = (start - h + ci) & (GRID_N - 1);

                // load 32 gate logits for this column, sigmoid inline
                float tw[32];
                #pragma unroll
                for (int c = 0; c < 32; ++c) {
                    const float v = twl[c * GRID_N + g];
                    tw[c] = __builtin_amdgcn_rcpf(1.0f + __expf(-v));
                }

                #pragma unroll
                for (int bb = 0; bb < 8; ++bb) {
                    const int b = ty * 8 + bb;
                    const float s0 = st[b][j - 2];
                    const float s1 = st[b][j - 1];
                    const float s2 = st[b][j];
                    const float s3 = st[b][j + 1];
                    const float s4 = st[b][j + 2];

                    // 5-level lerp tree == multilinear interpolation of tw
                    // bit order: bitmask[c][i] = bit (4-i) of c; s_i = state[n+i-2]
                    float u[16];
                    #pragma unroll
                    for (int r = 0; r < 16; ++r)
                        u[r] = fmaf(s0, tw[16 + r] - tw[r], tw[r]);
                    #pragma unroll
                    for (int r = 0; r < 8; ++r)
                        u[r] = fmaf(s1, u[8 + r] - u[r], u[r]);
                    #pragma unroll
                    for (int r = 0; r < 4; ++r)
                        u[r] = fmaf(s2, u[4 + r] - u[r], u[r]);
                    #pragma unroll
                    for (int r = 0; r < 2; ++r)
                        u[r] = fmaf(s3, u[2 + r] - u[r], u[r]);
                    float res = fmaf(s4, u[1] - u[0], u[0]);
                    res = fminf(fmaxf(res, 0.0f), 1.0f);
                    newv[p][bb] = res;
                }
            }
        }
        __syncthreads();
        #pragma unroll
        for (int p = 0; p < 2; ++p) {
            const int ci = tx + p * 64;
            if (ci < ncols) {
                const int j = jbase + ci;
                #pragma unroll
                for (int bb = 0; bb < 8; ++bb)
                    st[ty * 8 + bb][j] = newv[p][bb];
            }
        }
        __syncthreads();
    }

    // ---- output: state[:, ::4] for this tile's 64 owned columns ----
    {
        const int g = start + tx;
        if ((g & 3) == 0) {
            const int m = g >> 2;
            #pragma unroll
            for (int bb = 0; bb < 8; ++bb) {
                const int b = ty * 8 + bb;
                out[b * MW + m] = st[b][HALO + tx];
            }
        }
    }
}

extern "C" void kernel_launch(void* const* d_in, const int* in_sizes, int n_in,
                              void* d_out, int out_size, void* d_ws, size_t ws_size,
                              hipStream_t stream) {
    const float* x  = (const float*)d_in[0];   // (32, 4096)
    const float* tg = (const float*)d_in[1];   // (8, 32, 16384)
    float* out = (float*)d_out;                // (32, 4096)
    ASIC_44186623541335_kernel<<<GRID_N / TILE, 256, 0, stream>>>(x, tg, out);
}

// Round 2
// 81.793 us; speedup vs baseline: 1.1439x; 1.1439x over previous
//
#include <hip/hip_runtime.h>

#define GRID_N 16384
#define NLAYERS 8
#define NPOS 32
#define BATCH 32
#define MW 4096          // output width
#define TILE 32
#define HALO 16          // 2 * NLAYERS
#define WBUF 64          // TILE + 2*HALO
#define TWPAD 33         // pad 32->33 floats: conflict-free column access

// Multilinear-lerp ASIC automaton, v2.
// 512 blocks (2/CU) x 256 threads. Block = 32-col tile (+16 halo/side) x 32 batches.
// tw staged once/block via LDS (sigmoid computed once), register-prefetched 1 layer ahead.
// tx = lane = column (single pass, ncols<=60); ty = 0..3 -> batches ty*8..+7.
__global__ __launch_bounds__(256) void ASIC_44186623541335_kernel(
    const float* __restrict__ x,    // (32, 4096)
    const float* __restrict__ tg,   // (8, 32, 16384) raw logits
    float* __restrict__ out)        // (32, 4096)
{
    __shared__ float st[BATCH][WBUF];     // 8 KB
    __shared__ float twl[WBUF][TWPAD];    // 8.25 KB, sigmoided gates for current layer

    const int tid = threadIdx.x;
    const int tx  = tid & 63;       // column slot 0..63
    const int ty  = tid >> 6;       // 0..3
    const int start = blockIdx.x * TILE;
    const int gcol  = (start - HALO + tx) & (GRID_N - 1);  // global col for slot tx

    float pf[8];  // prefetched raw logits; thread covers c = ty + 4k, k=0..7, col = tx

    // ---- issue loads for layer 0 (coalesced: lanes = consecutive columns) ----
    #pragma unroll
    for (int k = 0; k < 8; ++k) {
        const int c = ty + 4 * k;
        pf[k] = tg[(size_t)c * GRID_N + gcol];
    }

    // ---- init state: embed x at stride 4, zeros elsewhere ----
    for (int f = tid; f < BATCH * WBUF; f += 256) {
        const int b = f >> 6;
        const int j = f & 63;
        const int g = (start - HALO + j) & (GRID_N - 1);
        st[b][j] = ((g & 3) == 0) ? x[b * MW + (g >> 2)] : 0.0f;
    }

    // ---- sigmoid + stage layer 0; issue prefetch for layer 1 ----
    #pragma unroll
    for (int k = 0; k < 8; ++k) {
        const int c = ty + 4 * k;
        twl[tx][c] = __builtin_amdgcn_rcpf(1.0f + __expf(-pf[k]));
    }
    #pragma unroll
    for (int k = 0; k < 8; ++k) {
        const int c = ty + 4 * k;
        pf[k] = tg[(size_t)NPOS * GRID_N + (size_t)c * GRID_N + gcol];
    }
    __syncthreads();

    float newv[8];
    for (int l = 0; l < NLAYERS; ++l) {
        const int h     = 2 * (NLAYERS - 1 - l);  // halo needed after this layer
        const int ncols = TILE + 2 * h;           // columns computed this layer (<=60)
        const int j     = (HALO - h) + tx;        // local state/gate index
        const bool act  = tx < ncols;

        if (act) {
            // gates for this column -> registers, reused across 8 batches
            float tw[32];
            #pragma unroll
            for (int c = 0; c < 32; ++c) tw[c] = twl[j][c];

            #pragma unroll
            for (int bb = 0; bb < 8; ++bb) {
                const int b = ty * 8 + bb;
                const float s0 = st[b][j - 2];
                const float s1 = st[b][j - 1];
                const float s2 = st[b][j];
                const float s3 = st[b][j + 1];
                const float s4 = st[b][j + 2];

                // 5-level lerp tree == multilinear interpolation of tw
                float u[16];
                #pragma unroll
                for (int r = 0; r < 16; ++r)
                    u[r] = fmaf(s0, tw[16 + r] - tw[r], tw[r]);
                #pragma unroll
                for (int r = 0; r < 8; ++r)
                    u[r] = fmaf(s1, u[8 + r] - u[r], u[r]);
                #pragma unroll
                for (int r = 0; r < 4; ++r)
                    u[r] = fmaf(s2, u[4 + r] - u[r], u[r]);
                #pragma unroll
                for (int r = 0; r < 2; ++r)
                    u[r] = fmaf(s3, u[2 + r] - u[r], u[r]);
                float res = fmaf(s4, u[1] - u[0], u[0]);
                newv[bb] = fminf(fmaxf(res, 0.0f), 1.0f);
            }
        }
        __syncthreads();

        if (act) {
            #pragma unroll
            for (int bb = 0; bb < 8; ++bb)
                st[ty * 8 + bb][j] = newv[bb];
        }
        if (l < NLAYERS - 1) {
            // stage next layer's gates (prefetched regs -> sigmoid -> LDS)
            #pragma unroll
            for (int k = 0; k < 8; ++k) {
                const int c = ty + 4 * k;
                twl[tx][c] = __builtin_amdgcn_rcpf(1.0f + __expf(-pf[k]));
            }
            if (l + 2 < NLAYERS) {
                const float* tn = tg + (size_t)(l + 2) * NPOS * GRID_N;
                #pragma unroll
                for (int k = 0; k < 8; ++k) {
                    const int c = ty + 4 * k;
                    pf[k] = tn[(size_t)c * GRID_N + gcol];
                }
            }
        }
        __syncthreads();
    }

    // ---- output: state[:, ::4] for this tile's 32 owned columns (8 outputs) ----
    if (tx < TILE && (tx & 3) == 0) {
        const int m = (start + tx) >> 2;
        #pragma unroll
        for (int bb = 0; bb < 8; ++bb) {
            const int b = ty * 8 + bb;
            out[b * MW + m] = st[b][HALO + tx];
        }
    }
}

extern "C" void kernel_launch(void* const* d_in, const int* in_sizes, int n_in,
                              void* d_out, int out_size, void* d_ws, size_t ws_size,
                              hipStream_t stream) {
    const float* x  = (const float*)d_in[0];   // (32, 4096)
    const float* tg = (const float*)d_in[1];   // (8, 32, 16384)
    float* out = (float*)d_out;                // (32, 4096)
    ASIC_44186623541335_kernel<<<GRID_N / TILE, 256, 0, stream>>>(x, tg, out);
}

// Round 3
// 81.239 us; speedup vs baseline: 1.1517x; 1.0068x over previous
//
#include <hip/hip_runtime.h>

#define GRID_N 16384
#define NLAYERS 8
#define NPOS 32
#define BATCH 32
#define MW 4096          // output width
#define TILE 32
#define HALO 16          // 2 * NLAYERS
#define WBUF 64          // TILE + 2*HALO
#define ROWP 36          // padded row stride (floats): 144B = 16B-aligned, max 2-way bank alias (free)

struct F2 { float a, b; };

// v3: 512 blocks x 512 threads (2 blocks/CU, 4 waves/SIMD).
// Block = 32-col tile (+16 halo/side) x 32 batches; thread = 1 column-slot x 4 batches.
// State & gates transposed to [col][elem] rows of 36 floats -> all LDS as b128.
// Double-buffered st+twl: ONE barrier per layer. Gate logits register-prefetched
// one layer ahead; sigmoid computed once per (layer, col, gate).
__global__ __launch_bounds__(512, 4) void ASIC_44186623541335_kernel(
    const float* __restrict__ x,    // (32, 4096)
    const float* __restrict__ tg,   // (8, 32, 16384) raw logits
    float* __restrict__ out)        // (32, 4096)
{
    __shared__ __align__(16) float st[2][WBUF][ROWP];    // state, rows = col slot, cols = batch
    __shared__ __align__(16) float twl[2][WBUF][ROWP];   // gates, rows = col slot, cols = gate idx

    const int tid = threadIdx.x;
    const int tx  = tid & 63;        // column slot 0..63 (lane)
    const int ty  = tid >> 6;        // 0..7 -> batches 4ty..4ty+3, gates 4ty..4ty+3
    const int c0  = 4 * ty;
    const int start = blockIdx.x * TILE;
    const int gcol  = (start - HALO + tx) & (GRID_N - 1);

    float pf[4];
    // ---- issue gate loads for layer 0 (coalesced: lanes = consecutive columns) ----
    #pragma unroll
    for (int k = 0; k < 4; ++k)
        pf[k] = tg[(size_t)(c0 + k) * GRID_N + gcol];

    // ---- init state buf0: embed x at stride 4, zeros elsewhere ----
    for (int f = tid; f < WBUF * BATCH; f += 512) {
        const int j = f >> 5;
        const int b = f & 31;
        const int g = (start - HALO + j) & (GRID_N - 1);
        st[0][j][b] = ((g & 3) == 0) ? x[b * MW + (g >> 2)] : 0.0f;
    }

    // ---- sigmoid + stage layer-0 gates; prefetch layer 1 ----
    {
        float4 sg;
        sg.x = __builtin_amdgcn_rcpf(1.0f + __expf(-pf[0]));
        sg.y = __builtin_amdgcn_rcpf(1.0f + __expf(-pf[1]));
        sg.z = __builtin_amdgcn_rcpf(1.0f + __expf(-pf[2]));
        sg.w = __builtin_amdgcn_rcpf(1.0f + __expf(-pf[3]));
        *(float4*)&twl[0][tx][c0] = sg;
        #pragma unroll
        for (int k = 0; k < 4; ++k)
            pf[k] = tg[(size_t)NPOS * GRID_N + (size_t)(c0 + k) * GRID_N + gcol];
    }
    __syncthreads();

    #pragma unroll
    for (int l = 0; l < NLAYERS; ++l) {
        const int h     = 2 * (NLAYERS - 1 - l);
        const int ncols = TILE + 2 * h;          // 60,56,...,32
        const int j     = (HALO - h) + tx;
        const int rb    = l & 1, wb = rb ^ 1;

        // ---- stage next layer's gates (consume pf), then prefetch layer l+2 ----
        if (l < NLAYERS - 1) {
            float4 sg;
            sg.x = __builtin_amdgcn_rcpf(1.0f + __expf(-pf[0]));
            sg.y = __builtin_amdgcn_rcpf(1.0f + __expf(-pf[1]));
            sg.z = __builtin_amdgcn_rcpf(1.0f + __expf(-pf[2]));
            sg.w = __builtin_amdgcn_rcpf(1.0f + __expf(-pf[3]));
            *(float4*)&twl[wb][tx][c0] = sg;
        }
        if (l + 2 < NLAYERS) {
            const float* tn = tg + (size_t)(l + 2) * NPOS * GRID_N;
            #pragma unroll
            for (int k = 0; k < 4; ++k)
                pf[k] = tn[(size_t)(c0 + k) * GRID_N + gcol];
        }

        if (tx < ncols) {
            // gates for this column -> 32 regs via 8x b128
            float tw[32];
            #pragma unroll
            for (int k = 0; k < 8; ++k) {
                const float4 q = *(const float4*)&twl[rb][j][4 * k];
                tw[4 * k]     = q.x; tw[4 * k + 1] = q.y;
                tw[4 * k + 2] = q.z; tw[4 * k + 3] = q.w;
            }
            // batch-invariant level-0 diffs (shared across 4 batches)
            float d0[16];
            #pragma unroll
            for (int r = 0; r < 16; ++r) d0[r] = tw[16 + r] - tw[r];

            // 5 neighbor columns x 4 batches via b128
            float4 S0 = *(const float4*)&st[rb][j - 2][c0];
            float4 S1 = *(const float4*)&st[rb][j - 1][c0];
            float4 S2 = *(const float4*)&st[rb][j    ][c0];
            float4 S3 = *(const float4*)&st[rb][j + 1][c0];
            float4 S4 = *(const float4*)&st[rb][j + 2][c0];

            float4 res;
            #pragma unroll
            for (int p = 0; p < 2; ++p) {
                const float s0a = p ? S0.z : S0.x, s0b = p ? S0.w : S0.y;
                const float s1a = p ? S1.z : S1.x, s1b = p ? S1.w : S1.y;
                const float s2a = p ? S2.z : S2.x, s2b = p ? S2.w : S2.y;
                const float s3a = p ? S3.z : S3.x, s3b = p ? S3.w : S3.y;
                const float s4a = p ? S4.z : S4.x, s4b = p ? S4.w : S4.y;

                F2 u[16];
                #pragma unroll
                for (int r = 0; r < 16; ++r) {
                    u[r].a = fmaf(s0a, d0[r], tw[r]);
                    u[r].b = fmaf(s0b, d0[r], tw[r]);
                }
                #pragma unroll
                for (int r = 0; r < 8; ++r) {
                    const float da = u[8 + r].a - u[r].a, db = u[8 + r].b - u[r].b;
                    u[r].a = fmaf(s1a, da, u[r].a);
                    u[r].b = fmaf(s1b, db, u[r].b);
                }
                #pragma unroll
                for (int r = 0; r < 4; ++r) {
                    const float da = u[4 + r].a - u[r].a, db = u[4 + r].b - u[r].b;
                    u[r].a = fmaf(s2a, da, u[r].a);
                    u[r].b = fmaf(s2b, db, u[r].b);
                }
                #pragma unroll
                for (int r = 0; r < 2; ++r) {
                    const float da = u[2 + r].a - u[r].a, db = u[2 + r].b - u[r].b;
                    u[r].a = fmaf(s3a, da, u[r].a);
                    u[r].b = fmaf(s3b, db, u[r].b);
                }
                const float da = u[1].a - u[0].a, db = u[1].b - u[0].b;
                float ra = fmaf(s4a, da, u[0].a);
                float rbv = fmaf(s4b, db, u[0].b);
                ra  = fminf(fmaxf(ra, 0.0f), 1.0f);
                rbv = fminf(fmaxf(rbv, 0.0f), 1.0f);
                if (p) { res.z = ra; res.w = rbv; } else { res.x = ra; res.y = rbv; }
            }
            *(float4*)&st[wb][j][c0] = res;
        }
        __syncthreads();
    }

    // ---- output: state[:, ::4]; final state is in buf 0 (8 layers, ping-pong) ----
    if (tid < 256) {
        const int c4 = tid & 7;          // 0..7: output column within tile
        const int b  = tid >> 3;         // 0..31
        out[b * MW + (start >> 2) + c4] = st[0][HALO + 4 * c4][b];
    }
}

extern "C" void kernel_launch(void* const* d_in, const int* in_sizes, int n_in,
                              void* d_out, int out_size, void* d_ws, size_t ws_size,
                              hipStream_t stream) {
    const float* x  = (const float*)d_in[0];   // (32, 4096)
    const float* tg = (const float*)d_in[1];   // (8, 32, 16384)
    float* out = (float*)d_out;                // (32, 4096)
    ASIC_44186623541335_kernel<<<GRID_N / TILE, 512, 0, stream>>>(x, tg, out);
}